// Round 10
// baseline (284.668 us; speedup 1.0000x reference)
//
#include <hip/hip_runtime.h>
#include <hip/hip_bf16.h>

typedef _Float16 f16x8 __attribute__((ext_vector_type(8)));
typedef float f32x4 __attribute__((ext_vector_type(4)));

#define MFMA16(a, b, c) __builtin_amdgcn_mfma_f32_16x16x32_f16(a, b, c, 0, 0, 0)

__device__ __forceinline__ void load_lds16(const void* g, void* l) {
  __builtin_amdgcn_global_load_lds(
      (__attribute__((address_space(1))) void*)g,
      (__attribute__((address_space(3))) void*)l, 16, 0, 0);
}

// ---------------- fast zero fill (16B/thread) — replaces 77us rocclr fill ----------------
__global__ __launch_bounds__(256) void k_fill0(f16x8* __restrict__ out, int n16) {
  int i = blockIdx.x * blockDim.x + threadIdx.x;
  if (i < n16) out[i] = f16x8{};
}

// ---------------- f32 -> f16 convert (8 elems / thread / iter) ----------------
__global__ __launch_bounds__(256) void k_cvt16(const float* __restrict__ in,
                                               _Float16* __restrict__ out, int n8) {
  int stride = gridDim.x * blockDim.x;
  for (int i = blockIdx.x * blockDim.x + threadIdx.x; i < n8; i += stride) {
    const float4* p = (const float4*)(in + (size_t)i * 8);
    float4 a = p[0], b = p[1];
    f16x8 v = {(_Float16)a.x, (_Float16)a.y, (_Float16)a.z, (_Float16)a.w,
               (_Float16)b.x, (_Float16)b.y, (_Float16)b.z, (_Float16)b.w};
    *(f16x8*)(out + (size_t)i * 8) = v;
  }
}

// ---------- transpose + convert: in[K][N] f32 -> out[N][K] f16, 64x64 tiles ----------
__global__ __launch_bounds__(256) void k_transpose(const float* __restrict__ in,
                                                   _Float16* __restrict__ out, int K, int N) {
  __shared__ float tile[64][65];
  int k0 = blockIdx.y * 64, n0 = blockIdx.x * 64;
  int t = threadIdx.x;
  {
    int nn = t & 63, kb = t >> 6;
#pragma unroll
    for (int i = 0; i < 16; ++i) {
      int kk = kb + i * 4;
      tile[kk][nn] = in[(size_t)(k0 + kk) * N + n0 + nn];
    }
  }
  __syncthreads();
  {
    int kk = t & 63, nb = t >> 6;
#pragma unroll
    for (int i = 0; i < 16; ++i) {
      int nn = nb + i * 4;
      out[(size_t)(n0 + nn) * K + k0 + kk] = (_Float16)tile[kk][nn];
    }
  }
}

// ---------------- K/V projection: ctxh[616][768] @ W^T -> heads ----------------
__global__ __launch_bounds__(64) void k_kvproj(const _Float16* __restrict__ ctxh,
                                               const _Float16* __restrict__ Wkt,
                                               const _Float16* __restrict__ Wvt,
                                               _Float16* __restrict__ Kg,
                                               _Float16* __restrict__ Vtg) {
  int mt = blockIdx.x, nt = blockIdx.y;
  int lane = threadIdx.x;
  int l15 = lane & 15, lhi = lane >> 4;
  int arow = mt * 16 + l15;
  if (arow > 615) arow = 615;  // clamp; masked at write
  const _Float16* ap = ctxh + (size_t)arow * 768 + lhi * 8;
  const _Float16* kp = Wkt + (size_t)(nt * 16 + l15) * 768 + lhi * 8;
  const _Float16* vp = Wvt + (size_t)(nt * 16 + l15) * 768 + lhi * 8;
  f32x4 ak = {0.f, 0.f, 0.f, 0.f}, av = {0.f, 0.f, 0.f, 0.f};
#pragma unroll 4
  for (int ks = 0; ks < 24; ++ks) {
    f16x8 a = *(const f16x8*)(ap + ks * 32);
    f16x8 bk = *(const f16x8*)(kp + ks * 32);
    f16x8 bv = *(const f16x8*)(vp + ks * 32);
    ak = MFMA16(a, bk, ak);
    av = MFMA16(a, bv, av);
  }
  int n = nt * 16 + l15, h = n >> 6, d = n & 63;
#pragma unroll
  for (int j = 0; j < 4; ++j) {
    int gm = mt * 16 + lhi * 4 + j;
    if (gm < 616) {
      int b = gm / 77, m = gm - b * 77;
      Kg[((size_t)(b * 16 + h) * 77 + m) * 64 + d] = (_Float16)ak[j];
      Vtg[((size_t)(b * 16 + h) * 64 + d) * 128 + m] = (_Float16)av[j];
    }
  }
}

// ---------------- attention: one block = one (b,h) x 64 query rows ----------------
__global__ __launch_bounds__(256) void k_attn(const _Float16* __restrict__ Qh,
                                              const _Float16* __restrict__ Kg,
                                              const _Float16* __restrict__ Vtg,
                                              _Float16* __restrict__ Out) {
  __shared__ __align__(16) char Kl[80 * 128];
  __shared__ __align__(16) char Vl[64 * 256];
  __shared__ __align__(16) char Pl[4 * 16 * 256];
  int bh = blockIdx.y, b = bh >> 4, h = bh & 15;
  int t = threadIdx.x, wid = t >> 6, lane = t & 63;
  int l15 = lane & 15, lhi = lane >> 4;

  const _Float16* Kgp = Kg + (size_t)bh * (77 * 64);
  const _Float16* Vgp = Vtg + (size_t)bh * (64 * 128);

  for (int idx = t; idx < 640; idx += 256) {
    int m = idx >> 3, c = (idx & 7) * 8;
    f16x8 v = {};
    if (m < 77) v = *(const f16x8*)(Kgp + m * 64 + c);
    *(f16x8*)(Kl + ((m * 128 + c * 2) ^ ((m & 7) << 4))) = v;
  }
  for (int idx = t; idx < 1024; idx += 256) {
    int d = idx >> 4, c = (idx & 15) * 8;
    f16x8 v = *(const f16x8*)(Vgp + d * 128 + c);
    *(f16x8*)(Vl + ((d * 256 + c * 2) ^ ((d & 7) << 4))) = v;
  }
  char* myP = Pl + wid * 4096;
#pragma unroll
  for (int i = 0; i < 4; ++i) *(f16x8*)(myP + lane * 64 + i * 16) = f16x8{};
  __syncthreads();

  int qrow = b * 4096 + blockIdx.x * 64 + wid * 16 + l15;
  const _Float16* qp = Qh + (size_t)qrow * 1024 + h * 64 + lhi * 8;
  f16x8 q0 = *(const f16x8*)qp;
  f16x8 q1 = *(const f16x8*)(qp + 32);

  float e[5][4];
  float mx[4] = {-1e30f, -1e30f, -1e30f, -1e30f};
#pragma unroll
  for (int ct = 0; ct < 5; ++ct) {
    int m = ct * 16 + l15;
    int d0b = lhi * 16;
    f16x8 k0 = *(const f16x8*)(Kl + ((m * 128 + d0b) ^ ((m & 7) << 4)));
    f16x8 k1 = *(const f16x8*)(Kl + ((m * 128 + 64 + d0b) ^ ((m & 7) << 4)));
    f32x4 acc = {0.f, 0.f, 0.f, 0.f};
    acc = MFMA16(q0, k0, acc);
    acc = MFMA16(q1, k1, acc);
    bool valid = m < 77;
#pragma unroll
    for (int j = 0; j < 4; ++j) {
      float v = valid ? acc[j] * 0.125f : -1e30f;
      e[ct][j] = v;
      mx[j] = fmaxf(mx[j], v);
    }
  }
#pragma unroll
  for (int off = 1; off < 16; off <<= 1)
#pragma unroll
    for (int j = 0; j < 4; ++j) mx[j] = fmaxf(mx[j], __shfl_xor(mx[j], off, 64));
  float sm[4] = {0.f, 0.f, 0.f, 0.f};
#pragma unroll
  for (int ct = 0; ct < 5; ++ct)
#pragma unroll
    for (int j = 0; j < 4; ++j) {
      float ev = __expf(e[ct][j] - mx[j]);
      e[ct][j] = ev;
      sm[j] += ev;
    }
#pragma unroll
  for (int off = 1; off < 16; off <<= 1)
#pragma unroll
    for (int j = 0; j < 4; ++j) sm[j] += __shfl_xor(sm[j], off, 64);
  float rs[4];
#pragma unroll
  for (int j = 0; j < 4; ++j) rs[j] = 1.0f / sm[j];

#pragma unroll
  for (int ct = 0; ct < 5; ++ct) {
    int m = ct * 16 + l15;
#pragma unroll
    for (int j = 0; j < 4; ++j) {
      int r = lhi * 4 + j;
      *(_Float16*)(myP + ((r * 256 + m * 2) ^ ((r & 7) << 4))) =
          (_Float16)(e[ct][j] * rs[j]);
    }
  }

  f32x4 o[4] = {{0.f,0.f,0.f,0.f},{0.f,0.f,0.f,0.f},{0.f,0.f,0.f,0.f},{0.f,0.f,0.f,0.f}};
#pragma unroll
  for (int ks = 0; ks < 3; ++ks) {
    int m0b = ks * 64 + lhi * 16;
    f16x8 pa = *(const f16x8*)(myP + ((l15 * 256 + m0b) ^ ((l15 & 7) << 4)));
#pragma unroll
    for (int dt = 0; dt < 4; ++dt) {
      int d = dt * 16 + l15;
      f16x8 vb = *(const f16x8*)(Vl + ((d * 256 + m0b) ^ ((d & 7) << 4)));
      o[dt] = MFMA16(pa, vb, o[dt]);
    }
  }
  _Float16* op = Out + (size_t)(b * 4096 + blockIdx.x * 64 + wid * 16) * 1024 + h * 64;
#pragma unroll
  for (int dt = 0; dt < 4; ++dt)
#pragma unroll
    for (int j = 0; j < 4; ++j) {
      int r = lhi * 4 + j;
      op[(size_t)r * 1024 + dt * 16 + l15] = (_Float16)o[dt][j];
    }
}

// ====== 256x256 GEMM, cluster-pipelined reads + true double-buffer (R9, 907 TF) ======
// A [M][K] f16, Bt [N][K] f16. BK=64, 512 thr = 8 waves (2Mx4N), wave C = 128x64.
// LDS: 2 bufs x (A 32KB + B 32KB). During tile t we stage tile t+1 into the OTHER
// buffer -> ONE vmcnt(0)+barrier per tile, NO intra-tile barriers.
// 8 clusters of 8 MFMA16 per tile; cluster ds_reads issued ONE CLUSTER AHEAD
// (compiler emits minimal counted lgkmcnt per use -> partial waits for free).
// Swizzle: conflict-free (store chunk c^(r&7); pre-swizzled global source;
// INT-offset reads cs0/cs1 — no pointer bit-ops, R7 lesson).
template <int FINAL>
__global__ __launch_bounds__(512, 2) void k_gemm7(const _Float16* __restrict__ A,
                                                  const _Float16* __restrict__ Bt,
                                                  void* __restrict__ Cout,
                                                  const float* __restrict__ bias,
                                                  int M, int N, int K) {
  __shared__ __align__(16) char lds[131072];
  const int t = threadIdx.x, wid = t >> 6, lane = t & 63;
  const int wr = wid >> 2, wc = wid & 3;  // 2M x 4N wave grid
  const int l15 = lane & 15, lhi = lane >> 4;

  // T1: bijective XCD swizzle (nwg % 8 == 0)
  int nwg = gridDim.x, bid = blockIdx.x;
  int wg = ((nwg & 7) == 0) ? ((bid & 7) * (nwg >> 3) + (bid >> 3)) : bid;
  const int nTN = N >> 8;
  const int tm = wg / nTN, tn = wg % nTN;

  const _Float16* Ag = A + (size_t)tm * 256 * K;
  const _Float16* Bg = Bt + (size_t)tn * 256 * K;
  const size_t stg = (size_t)(wid * 8 + (lane >> 3)) * K +
                     (size_t)(((lane & 7) ^ ((lane >> 3) & 7)) * 8);
  const int dstg = wid * 1024;  // linear wave dest (HW adds lane*16)

  // read swizzle as int offsets: chunk(kk) = (kk*4 + lhi) ^ (l15&7)
  const int x7 = l15 & 7;
  const int cs0 = (lhi ^ x7) << 4;
  const int cs1 = ((4 + lhi) ^ x7) << 4;
  const int aoff = wr * 16384 + l15 * 128;
  const int boff = 32768 + wc * 8192 + l15 * 128;

  f32x4 acc[8][4];
#pragma unroll
  for (int i = 0; i < 8; ++i)
#pragma unroll
    for (int j = 0; j < 4; ++j) acc[i][j] = f32x4{0.f, 0.f, 0.f, 0.f};
  f16x8 a0k0[4], a0k1[4], a1k0[4], a1k1[4];
  f16x8 b00[2], b01[2], b10[2], b11[2];

#define STG_A(T, RB) load_lds16(Ag + stg + (size_t)(RB) * K + (T) * 64, \
                                lds + ((T) & 1) * 65536 + (RB) * 128 + dstg)
#define STG_B(T, RB) load_lds16(Bg + stg + (size_t)(RB) * K + (T) * 64, \
                                lds + ((T) & 1) * 65536 + 32768 + (RB) * 128 + dstg)
#define STG_TILE(T) { STG_A(T, 0); STG_A(T, 64); STG_A(T, 128); STG_A(T, 192);  \
                      STG_B(T, 0); STG_B(T, 64); STG_B(T, 128); STG_B(T, 192); }
#define RDA(DST, BUF, MH, CS) { const int p_ = (BUF) * 65536 + aoff + (MH) * 8192; \
    _Pragma("unroll") for (int mf = 0; mf < 4; ++mf)                               \
      DST[mf] = *(const f16x8*)&lds[p_ + mf * 2048 + (CS)]; }
#define RDB(DST, BUF, NH, CS) { const int q_ = (BUF) * 65536 + boff + (NH) * 4096; \
    _Pragma("unroll") for (int nf = 0; nf < 2; ++nf)                               \
      DST[nf] = *(const f16x8*)&lds[q_ + nf * 2048 + (CS)]; }
#define MMC(MH, NH, AR, BR) { __builtin_amdgcn_s_setprio(1);                       \
    _Pragma("unroll") for (int mf = 0; mf < 4; ++mf)                               \
      _Pragma("unroll") for (int nf = 0; nf < 2; ++nf)                             \
        acc[(MH)*4+mf][(NH)*2+nf] = MFMA16(AR[mf], BR[nf],                         \
                                           acc[(MH)*4+mf][(NH)*2+nf]);             \
    __builtin_amdgcn_s_setprio(0); }
#define VM0 asm volatile("s_waitcnt vmcnt(0)" ::: "memory")
#define BAR __builtin_amdgcn_s_barrier()

#define TILE(BUF, T, STG_ON)                                                       \
  {                                                                                \
    VM0; BAR;                                                                      \
    RDA(a0k0, BUF, 0, cs0); RDB(b00, BUF, 0, cs0);                                 \
    RDB(b10, BUF, 1, cs0);                                                         \
    if (STG_ON) STG_TILE((T) + 1);                                                 \
    MMC(0, 0, a0k0, b00);                                                          \
    RDA(a1k0, BUF, 1, cs0); MMC(0, 1, a0k0, b10);                                  \
    RDA(a1k1, BUF, 1, cs1); MMC(1, 1, a1k0, b10);                                  \
    RDB(b01, BUF, 0, cs1);  MMC(1, 0, a1k0, b00);                                  \
    RDB(b11, BUF, 1, cs1);  MMC(1, 0, a1k1, b01);                                  \
    RDA(a0k1, BUF, 0, cs1); MMC(1, 1, a1k1, b11);                                  \
    MMC(0, 1, a0k1, b11);                                                          \
    MMC(0, 0, a0k1, b01);                                                          \
  }

  const int nT = K >> 6;  // 16 for K=1024 (even, >= 4)

  STG_TILE(0);  // prologue: tile 0 -> buf0

  for (int i = 0; i < (nT >> 1) - 1; ++i) {
    TILE(0, 2 * i, true);
    TILE(1, 2 * i + 1, true);
  }
  TILE(0, nT - 2, true);   // stages tile nT-1 -> buf1
  TILE(1, nT - 1, false);  // last tile: nothing to stage

  // ---- C write: 16x16 C-layout col = l15, row = lhi*4 + reg (verified m89)
  const long rbase = (long)tm * 256 + wr * 128;
  const int cbase = tn * 256 + wc * 64;
#pragma unroll
  for (int mf = 0; mf < 8; ++mf)
#pragma unroll
    for (int nf = 0; nf < 4; ++nf) {
      int c = cbase + nf * 16 + l15;
      float bv = FINAL ? bias[c] : 0.f;
#pragma unroll
      for (int j = 0; j < 4; ++j) {
        long r = rbase + mf * 16 + lhi * 4 + j;
        float v = acc[mf][nf][j];
        if (FINAL) ((float*)Cout)[r * N + c] = v + bv;
        else ((_Float16*)Cout)[r * N + c] = (_Float16)v;
      }
    }
#undef STG_A
#undef STG_B
#undef STG_TILE
#undef RDA
#undef RDB
#undef MMC
#undef TILE
#undef VM0
#undef BAR
}

extern "C" void kernel_launch(void* const* d_in, const int* in_sizes, int n_in,
                              void* d_out, int out_size, void* d_ws, size_t ws_size,
                              hipStream_t stream) {
  const float* x   = (const float*)d_in[0];
  const float* ctx = (const float*)d_in[1];
  const float* Wq  = (const float*)d_in[2];
  const float* Wk  = (const float*)d_in[3];
  const float* Wv  = (const float*)d_in[4];
  const float* Wo  = (const float*)d_in[5];
  const float* bo  = (const float*)d_in[6];

  char* ws = (char*)d_ws;
  _Float16* xh   = (_Float16*)(ws + 0);           // [32768][1024] x-f16; later attnOut
  _Float16* Wqt  = (_Float16*)(ws + 67108864);    // [1024][1024]
  _Float16* Wkt  = (_Float16*)(ws + 69206016);    // [1024][768]
  _Float16* Wvt  = (_Float16*)(ws + 70778880);    // [1024][768]
  _Float16* Wot  = (_Float16*)(ws + 72351744);    // [1024][1024]
  _Float16* ctxh = (_Float16*)(ws + 74448896);    // [616][768]
  _Float16* Kg   = (_Float16*)(ws + 75395072);    // [128][77][64]
  _Float16* Vtg  = (_Float16*)(ws + 76656640);    // [128][64][128]
  _Float16* Qh   = (_Float16*)d_out;              // [32768][1024] f16 scratch in d_out

  k_cvt16<<<4096, 256, 0, stream>>>(x, xh, 33554432 / 8);
  k_cvt16<<<231, 256, 0, stream>>>(ctx, ctxh, 473088 / 8);
  k_transpose<<<dim3(16, 16), 256, 0, stream>>>(Wq, Wqt, 1024, 1024);
  k_transpose<<<dim3(16, 12), 256, 0, stream>>>(Wk, Wkt, 768, 1024);
  k_transpose<<<dim3(16, 12), 256, 0, stream>>>(Wv, Wvt, 768, 1024);
  k_transpose<<<dim3(16, 16), 256, 0, stream>>>(Wo, Wot, 1024, 1024);
  // zero Vtg (pad m in [77,128) must be finite; P=0 there so any finite value is
  // inert, but fresh memory can hold f16 NaN patterns). Custom fill: ~2us vs
  // rocclr fillBufferAligned's 77us (R9 profile).
  k_fill0<<<512, 256, 0, stream>>>((f16x8*)Vtg, 131072);
  k_kvproj<<<dim3(39, 64), 64, 0, stream>>>(ctxh, Wkt, Wvt, Kg, Vtg);
  // GEMM1: Q projection -> d_out (f16 scratch); grid 512 (%8==0 for T1)
  k_gemm7<0><<<dim3(512), dim3(512), 0, stream>>>(xh, Wqt, (void*)Qh, nullptr, 32768, 1024, 1024);
  // attention: reads Qh (d_out), writes attnOut -> xh
  k_attn<<<dim3(64, 128), 256, 0, stream>>>(Qh, Kg, Vtg, xh);
  // GEMM2: O projection + bias -> d_out (f32)
  k_gemm7<1><<<dim3(512), dim3(512), 0, stream>>>(xh, Wot, d_out, bo, 32768, 1024, 1024);
}

// Round 11
// 279.140 us; speedup vs baseline: 1.0198x; 1.0198x over previous
//
#include <hip/hip_runtime.h>
#include <hip/hip_bf16.h>

typedef _Float16 f16x8 __attribute__((ext_vector_type(8)));
typedef float f32x4 __attribute__((ext_vector_type(4)));
typedef float f32x16 __attribute__((ext_vector_type(16)));

#define MFMA16(a, b, c) __builtin_amdgcn_mfma_f32_16x16x32_f16(a, b, c, 0, 0, 0)
#define MFMA32(a, b, c) __builtin_amdgcn_mfma_f32_32x32x16_f16(a, b, c, 0, 0, 0)

__device__ __forceinline__ void load_lds16(const void* g, void* l) {
  __builtin_amdgcn_global_load_lds(
      (__attribute__((address_space(1))) void*)g,
      (__attribute__((address_space(3))) void*)l, 16, 0, 0);
}

// ============ prep kernel: cvt x, cvt ctx, 4 weight transposes, Vtg pad fill ============
// All independent; one kernel (block-range dispatch) replaces 7 launches -> saves
// inter-kernel ramp/drain gaps. Branch is on blockIdx -> block-uniform, sync-safe.
__global__ __launch_bounds__(256) void k_prep(const float* __restrict__ x,
                                              const float* __restrict__ ctx,
                                              const float* __restrict__ Wq,
                                              const float* __restrict__ Wk,
                                              const float* __restrict__ Wv,
                                              const float* __restrict__ Wo,
                                              _Float16* __restrict__ xh,
                                              _Float16* __restrict__ ctxh,
                                              _Float16* __restrict__ Wqt,
                                              _Float16* __restrict__ Wkt,
                                              _Float16* __restrict__ Wvt,
                                              _Float16* __restrict__ Wot,
                                              _Float16* __restrict__ Vtg) {
  __shared__ float tile[64][65];
  const int b = blockIdx.x, t = threadIdx.x;

  if (b < 4096) {  // ---- cvt x: 33554432 f32 -> f16, 8/thread/iter
    for (int i = b * 256 + t; i < 4194304; i += 4096 * 256) {
      const float4* p = (const float4*)(x + (size_t)i * 8);
      float4 a = p[0], c = p[1];
      f16x8 v = {(_Float16)a.x, (_Float16)a.y, (_Float16)a.z, (_Float16)a.w,
                 (_Float16)c.x, (_Float16)c.y, (_Float16)c.z, (_Float16)c.w};
      *(f16x8*)(xh + (size_t)i * 8) = v;
    }
    return;
  }
  if (b < 4327) {  // ---- cvt ctx: 473088 f32 (231*256*8 exact)
    int i = (b - 4096) * 256 + t;
    const float4* p = (const float4*)(ctx + (size_t)i * 8);
    float4 a = p[0], c = p[1];
    f16x8 v = {(_Float16)a.x, (_Float16)a.y, (_Float16)a.z, (_Float16)a.w,
               (_Float16)c.x, (_Float16)c.y, (_Float16)c.z, (_Float16)c.w};
    *(f16x8*)(ctxh + (size_t)i * 8) = v;
    return;
  }
  if (b >= 5223) {  // ---- zero Vtg pad region (512 blocks * 256 * 16B = 2MB exact)
    int i = (b - 5223) * 256 + t;
    ((f16x8*)Vtg)[i] = f16x8{};
    return;
  }
  // ---- weight transpose+convert: in[K][N] f32 -> out[N][K] f16, 64x64 tiles
  const float* tin;
  _Float16* tout;
  int TK, TN, i;
  if (b < 4583)      { tin = Wq; tout = Wqt; TK = 1024; TN = 1024; i = b - 4327; }
  else if (b < 4775) { tin = Wk; tout = Wkt; TK = 768;  TN = 1024; i = b - 4583; }
  else if (b < 4967) { tin = Wv; tout = Wvt; TK = 768;  TN = 1024; i = b - 4775; }
  else               { tin = Wo; tout = Wot; TK = 1024; TN = 1024; i = b - 4967; }
  int n0 = (i & 15) * 64, k0 = (i >> 4) * 64;
  {
    int nn = t & 63, kb = t >> 6;
#pragma unroll
    for (int s = 0; s < 16; ++s) {
      int kk = kb + s * 4;
      tile[kk][nn] = tin[(size_t)(k0 + kk) * TN + n0 + nn];
    }
  }
  __syncthreads();
  {
    int kk = t & 63, nb = t >> 6;
#pragma unroll
    for (int s = 0; s < 16; ++s) {
      int nn = nb + s * 4;
      tout[(size_t)(n0 + nn) * TK + k0 + kk] = (_Float16)tile[kk][nn];
    }
  }
}

// ---------------- K/V projection: ctxh[616][768] @ W^T -> heads ----------------
__global__ __launch_bounds__(64) void k_kvproj(const _Float16* __restrict__ ctxh,
                                               const _Float16* __restrict__ Wkt,
                                               const _Float16* __restrict__ Wvt,
                                               _Float16* __restrict__ Kg,
                                               _Float16* __restrict__ Vtg) {
  int mt = blockIdx.x, nt = blockIdx.y;
  int lane = threadIdx.x;
  int l15 = lane & 15, lhi = lane >> 4;
  int arow = mt * 16 + l15;
  if (arow > 615) arow = 615;  // clamp; masked at write
  const _Float16* ap = ctxh + (size_t)arow * 768 + lhi * 8;
  const _Float16* kp = Wkt + (size_t)(nt * 16 + l15) * 768 + lhi * 8;
  const _Float16* vp = Wvt + (size_t)(nt * 16 + l15) * 768 + lhi * 8;
  f32x4 ak = {0.f, 0.f, 0.f, 0.f}, av = {0.f, 0.f, 0.f, 0.f};
#pragma unroll 4
  for (int ks = 0; ks < 24; ++ks) {
    f16x8 a = *(const f16x8*)(ap + ks * 32);
    f16x8 bk = *(const f16x8*)(kp + ks * 32);
    f16x8 bv = *(const f16x8*)(vp + ks * 32);
    ak = MFMA16(a, bk, ak);
    av = MFMA16(a, bv, av);
  }
  int n = nt * 16 + l15, h = n >> 6, d = n & 63;
#pragma unroll
  for (int j = 0; j < 4; ++j) {
    int gm = mt * 16 + lhi * 4 + j;
    if (gm < 616) {
      int b = gm / 77, m = gm - b * 77;
      Kg[((size_t)(b * 16 + h) * 77 + m) * 64 + d] = (_Float16)ak[j];
      Vtg[((size_t)(b * 16 + h) * 64 + d) * 128 + m] = (_Float16)av[j];
    }
  }
}

// ---------------- attention: one block = one (b,h) x 64 query rows ----------------
__global__ __launch_bounds__(256) void k_attn(const _Float16* __restrict__ Qh,
                                              const _Float16* __restrict__ Kg,
                                              const _Float16* __restrict__ Vtg,
                                              _Float16* __restrict__ Out) {
  __shared__ __align__(16) char Kl[80 * 128];
  __shared__ __align__(16) char Vl[64 * 256];
  __shared__ __align__(16) char Pl[4 * 16 * 256];
  int bh = blockIdx.y, b = bh >> 4, h = bh & 15;
  int t = threadIdx.x, wid = t >> 6, lane = t & 63;
  int l15 = lane & 15, lhi = lane >> 4;

  const _Float16* Kgp = Kg + (size_t)bh * (77 * 64);
  const _Float16* Vgp = Vtg + (size_t)bh * (64 * 128);

  for (int idx = t; idx < 640; idx += 256) {
    int m = idx >> 3, c = (idx & 7) * 8;
    f16x8 v = {};
    if (m < 77) v = *(const f16x8*)(Kgp + m * 64 + c);
    *(f16x8*)(Kl + ((m * 128 + c * 2) ^ ((m & 7) << 4))) = v;
  }
  for (int idx = t; idx < 1024; idx += 256) {
    int d = idx >> 4, c = (idx & 15) * 8;
    f16x8 v = *(const f16x8*)(Vgp + d * 128 + c);
    *(f16x8*)(Vl + ((d * 256 + c * 2) ^ ((d & 7) << 4))) = v;
  }
  char* myP = Pl + wid * 4096;
#pragma unroll
  for (int i = 0; i < 4; ++i) *(f16x8*)(myP + lane * 64 + i * 16) = f16x8{};
  __syncthreads();

  int qrow = b * 4096 + blockIdx.x * 64 + wid * 16 + l15;
  const _Float16* qp = Qh + (size_t)qrow * 1024 + h * 64 + lhi * 8;
  f16x8 q0 = *(const f16x8*)qp;
  f16x8 q1 = *(const f16x8*)(qp + 32);

  float e[5][4];
  float mx[4] = {-1e30f, -1e30f, -1e30f, -1e30f};
#pragma unroll
  for (int ct = 0; ct < 5; ++ct) {
    int m = ct * 16 + l15;
    int d0b = lhi * 16;
    f16x8 k0 = *(const f16x8*)(Kl + ((m * 128 + d0b) ^ ((m & 7) << 4)));
    f16x8 k1 = *(const f16x8*)(Kl + ((m * 128 + 64 + d0b) ^ ((m & 7) << 4)));
    f32x4 acc = {0.f, 0.f, 0.f, 0.f};
    acc = MFMA16(q0, k0, acc);
    acc = MFMA16(q1, k1, acc);
    bool valid = m < 77;
#pragma unroll
    for (int j = 0; j < 4; ++j) {
      float v = valid ? acc[j] * 0.125f : -1e30f;
      e[ct][j] = v;
      mx[j] = fmaxf(mx[j], v);
    }
  }
#pragma unroll
  for (int off = 1; off < 16; off <<= 1)
#pragma unroll
    for (int j = 0; j < 4; ++j) mx[j] = fmaxf(mx[j], __shfl_xor(mx[j], off, 64));
  float sm[4] = {0.f, 0.f, 0.f, 0.f};
#pragma unroll
  for (int ct = 0; ct < 5; ++ct)
#pragma unroll
    for (int j = 0; j < 4; ++j) {
      float ev = __expf(e[ct][j] - mx[j]);
      e[ct][j] = ev;
      sm[j] += ev;
    }
#pragma unroll
  for (int off = 1; off < 16; off <<= 1)
#pragma unroll
    for (int j = 0; j < 4; ++j) sm[j] += __shfl_xor(sm[j], off, 64);
  float rs[4];
#pragma unroll
  for (int j = 0; j < 4; ++j) rs[j] = 1.0f / sm[j];

#pragma unroll
  for (int ct = 0; ct < 5; ++ct) {
    int m = ct * 16 + l15;
#pragma unroll
    for (int j = 0; j < 4; ++j) {
      int r = lhi * 4 + j;
      *(_Float16*)(myP + ((r * 256 + m * 2) ^ ((r & 7) << 4))) =
          (_Float16)(e[ct][j] * rs[j]);
    }
  }

  f32x4 o[4] = {{0.f,0.f,0.f,0.f},{0.f,0.f,0.f,0.f},{0.f,0.f,0.f,0.f},{0.f,0.f,0.f,0.f}};
#pragma unroll
  for (int ks = 0; ks < 3; ++ks) {
    int m0b = ks * 64 + lhi * 16;
    f16x8 pa = *(const f16x8*)(myP + ((l15 * 256 + m0b) ^ ((l15 & 7) << 4)));
#pragma unroll
    for (int dt = 0; dt < 4; ++dt) {
      int d = dt * 16 + l15;
      f16x8 vb = *(const f16x8*)(Vl + ((d * 256 + m0b) ^ ((d & 7) << 4)));
      o[dt] = MFMA16(pa, vb, o[dt]);
    }
  }
  _Float16* op = Out + (size_t)(b * 4096 + blockIdx.x * 64 + wid * 16) * 1024 + h * 64;
#pragma unroll
  for (int dt = 0; dt < 4; ++dt)
#pragma unroll
    for (int j = 0; j < 4; ++j) {
      int r = lhi * 4 + j;
      op[(size_t)r * 1024 + dt * 16 + l15] = (_Float16)o[dt][j];
    }
}

// ====== 256x256 GEMM: R9 schedule + mfma_f32_32x32x16_f16 (R4-verified mapping) ======
// A [M][K] f16, Bt [N][K] f16. BK=64, 512 thr = 8 waves (2Mx4N), wave C = 128x64 as
// 4 m-frags x 2 n-frags of 32x32. LDS: 2 bufs x (A 32KB + B 32KB); stage t+1 into
// the OTHER buffer during tile t -> ONE vmcnt(0)+barrier per tile. 4 clusters of
// 8 MFMA32 per tile; cluster ds_reads issued one cluster ahead (ping-pong frag sets).
// A-frag (32x32x16): lane holds A[row=l31][k = hi*8+j] -> chunk = ks*2+hi of the
// 128B row; swizzle chunk ^= row&7 (conflict-free; R8-verified) via INT offsets.
// C-layout: col = l31, row = (reg&3) + 8*(reg>>2) + 4*hi  [R4 pass-verified].
template <int FINAL>
__global__ __launch_bounds__(512, 2) void k_gemm8(const _Float16* __restrict__ A,
                                                  const _Float16* __restrict__ Bt,
                                                  void* __restrict__ Cout,
                                                  const float* __restrict__ bias,
                                                  int M, int N, int K) {
  __shared__ __align__(16) char lds[131072];
  const int t = threadIdx.x, wid = t >> 6, lane = t & 63;
  const int wr = wid >> 2, wc = wid & 3;  // 2M x 4N wave grid
  const int l31 = lane & 31, hi = lane >> 5;

  // T1: bijective XCD swizzle (nwg % 8 == 0)
  int nwg = gridDim.x, bid = blockIdx.x;
  int wg = ((nwg & 7) == 0) ? ((bid & 7) * (nwg >> 3) + (bid >> 3)) : bid;
  const int nTN = N >> 8;
  const int tm = wg / nTN, tn = wg % nTN;

  const _Float16* Ag = A + (size_t)tm * 256 * K;
  const _Float16* Bg = Bt + (size_t)tn * 256 * K;
  const size_t stg = (size_t)(wid * 8 + (lane >> 3)) * K +
                     (size_t)(((lane & 7) ^ ((lane >> 3) & 7)) * 8);
  const int dstg = wid * 1024;  // linear wave dest (HW adds lane*16)

  // read swizzle (int offsets): chunk(ks) = (ks*2 + hi) ^ (l31&7)
  const int x7 = l31 & 7;
  const int cka = ((0 + hi) ^ x7) << 4;
  const int ckb = ((2 + hi) ^ x7) << 4;
  const int ckc = ((4 + hi) ^ x7) << 4;
  const int ckd = ((6 + hi) ^ x7) << 4;
  const int abase = (wr * 128 + l31) * 128;           // + mf*4096 + ck
  const int bbase = 32768 + (wc * 64 + l31) * 128;    // + nf*4096 + ck

  f32x16 acc[4][2];
#pragma unroll
  for (int i = 0; i < 4; ++i) { acc[i][0] = f32x16{}; acc[i][1] = f32x16{}; }
  f16x8 xa0, xa1, xa2, xa3, xb0, xb1;  // frag set X
  f16x8 ya0, ya1, ya2, ya3, yb0, yb1;  // frag set Y

#define STG_A(T, RB) load_lds16(Ag + stg + (size_t)(RB) * K + (T) * 64, \
                                lds + ((T) & 1) * 65536 + (RB) * 128 + dstg)
#define STG_B(T, RB) load_lds16(Bg + stg + (size_t)(RB) * K + (T) * 64, \
                                lds + ((T) & 1) * 65536 + 32768 + (RB) * 128 + dstg)
#define STG_TILE(T) { STG_A(T, 0); STG_A(T, 64); STG_A(T, 128); STG_A(T, 192);  \
                      STG_B(T, 0); STG_B(T, 64); STG_B(T, 128); STG_B(T, 192); }
#define RDK(A0, A1, A2, A3, B0, B1, BUF, CK) {                                  \
    const int pa_ = (BUF) * 65536 + abase + (CK);                               \
    A0 = *(const f16x8*)&lds[pa_];                                              \
    A1 = *(const f16x8*)&lds[pa_ + 4096];                                       \
    A2 = *(const f16x8*)&lds[pa_ + 8192];                                       \
    A3 = *(const f16x8*)&lds[pa_ + 12288];                                      \
    const int pb_ = (BUF) * 65536 + bbase + (CK);                               \
    B0 = *(const f16x8*)&lds[pb_];                                              \
    B1 = *(const f16x8*)&lds[pb_ + 4096]; }
#define MMK(A0, A1, A2, A3, B0, B1) { __builtin_amdgcn_s_setprio(1);            \
    acc[0][0] = MFMA32(A0, B0, acc[0][0]); acc[0][1] = MFMA32(A0, B1, acc[0][1]); \
    acc[1][0] = MFMA32(A1, B0, acc[1][0]); acc[1][1] = MFMA32(A1, B1, acc[1][1]); \
    acc[2][0] = MFMA32(A2, B0, acc[2][0]); acc[2][1] = MFMA32(A2, B1, acc[2][1]); \
    acc[3][0] = MFMA32(A3, B0, acc[3][0]); acc[3][1] = MFMA32(A3, B1, acc[3][1]); \
    __builtin_amdgcn_s_setprio(0); }
#define VM0 asm volatile("s_waitcnt vmcnt(0)" ::: "memory")
#define BAR __builtin_amdgcn_s_barrier()

#define TILE(BUF, T, STG_ON)                                                    \
  {                                                                             \
    VM0; BAR;                                                                   \
    RDK(xa0, xa1, xa2, xa3, xb0, xb1, BUF, cka);                                \
    if (STG_ON) STG_TILE((T) + 1);                                              \
    RDK(ya0, ya1, ya2, ya3, yb0, yb1, BUF, ckb);                                \
    MMK(xa0, xa1, xa2, xa3, xb0, xb1);                                          \
    RDK(xa0, xa1, xa2, xa3, xb0, xb1, BUF, ckc);                                \
    MMK(ya0, ya1, ya2, ya3, yb0, yb1);                                          \
    RDK(ya0, ya1, ya2, ya3, yb0, yb1, BUF, ckd);                                \
    MMK(xa0, xa1, xa2, xa3, xb0, xb1);                                          \
    MMK(ya0, ya1, ya2, ya3, yb0, yb1);                                          \
  }

  const int nT = K >> 6;  // 16 for K=1024 (even, >= 2)

  STG_TILE(0);  // prologue: tile 0 -> buf0

  for (int i = 0; i < (nT >> 1) - 1; ++i) {
    TILE(0, 2 * i, true);
    TILE(1, 2 * i + 1, true);
  }
  TILE(0, nT - 2, true);   // stages tile nT-1 -> buf1
  TILE(1, nT - 1, false);  // last tile: nothing to stage

  // ---- C write: 32x32 layout col=l31, row=(reg&3)+8*(reg>>2)+4*hi (R4-verified)
  const long rbase = (long)tm * 256 + wr * 128;
  const int cbase = tn * 256 + wc * 64;
#pragma unroll
  for (int mf = 0; mf < 4; ++mf)
#pragma unroll
    for (int nf = 0; nf < 2; ++nf) {
      int c = cbase + nf * 32 + l31;
      float bv = FINAL ? bias[c] : 0.f;
#pragma unroll
      for (int reg = 0; reg < 16; ++reg) {
        long r = rbase + mf * 32 + (reg & 3) + ((reg >> 2) << 3) + (hi << 2);
        float v = acc[mf][nf][reg];
        if (FINAL) ((float*)Cout)[r * N + c] = v + bv;
        else ((_Float16*)Cout)[r * N + c] = (_Float16)v;
      }
    }
#undef STG_A
#undef STG_B
#undef STG_TILE
#undef RDK
#undef MMK
#undef TILE
#undef VM0
#undef BAR
}

extern "C" void kernel_launch(void* const* d_in, const int* in_sizes, int n_in,
                              void* d_out, int out_size, void* d_ws, size_t ws_size,
                              hipStream_t stream) {
  const float* x   = (const float*)d_in[0];
  const float* ctx = (const float*)d_in[1];
  const float* Wq  = (const float*)d_in[2];
  const float* Wk  = (const float*)d_in[3];
  const float* Wv  = (const float*)d_in[4];
  const float* Wo  = (const float*)d_in[5];
  const float* bo  = (const float*)d_in[6];

  char* ws = (char*)d_ws;
  _Float16* xh   = (_Float16*)(ws + 0);           // [32768][1024] x-f16; later attnOut
  _Float16* Wqt  = (_Float16*)(ws + 67108864);    // [1024][1024]
  _Float16* Wkt  = (_Float16*)(ws + 69206016);    // [1024][768]
  _Float16* Wvt  = (_Float16*)(ws + 70778880);    // [1024][768]
  _Float16* Wot  = (_Float16*)(ws + 72351744);    // [1024][1024]
  _Float16* ctxh = (_Float16*)(ws + 74448896);    // [616][768]
  _Float16* Kg   = (_Float16*)(ws + 75395072);    // [128][77][64]
  _Float16* Vtg  = (_Float16*)(ws + 76656640);    // [128][64][128]
  _Float16* Qh   = (_Float16*)d_out;              // [32768][1024] f16 scratch in d_out

  // prep: cvt x [0,4096) | cvt ctx [4096,4327) | T(Wq) [4327,4583) | T(Wk)
  // [4583,4775) | T(Wv) [4775,4967) | T(Wo) [4967,5223) | fill Vtg [5223,5735)
  k_prep<<<5735, 256, 0, stream>>>(x, ctx, Wq, Wk, Wv, Wo,
                                   xh, ctxh, Wqt, Wkt, Wvt, Wot, Vtg);
  k_kvproj<<<dim3(39, 64), 64, 0, stream>>>(ctxh, Wkt, Wvt, Kg, Vtg);
  // GEMM1: Q projection -> d_out (f16 scratch); grid 512 (%8==0 for T1)
  k_gemm8<0><<<dim3(512), dim3(512), 0, stream>>>(xh, Wqt, (void*)Qh, nullptr, 32768, 1024, 1024);
  // attention: reads Qh (d_out), writes attnOut -> xh
  k_attn<<<dim3(64, 128), 256, 0, stream>>>(Qh, Kg, Vtg, xh);
  // GEMM2: O projection + bias -> d_out (f32)
  k_gemm8<1><<<dim3(512), dim3(512), 0, stream>>>(xh, Wot, d_out, bo, 32768, 1024, 1024);
}

// Round 12
// 260.115 us; speedup vs baseline: 1.0944x; 1.0731x over previous
//
#include <hip/hip_runtime.h>
#include <hip/hip_bf16.h>

typedef _Float16 f16x8 __attribute__((ext_vector_type(8)));
typedef float f32x4 __attribute__((ext_vector_type(4)));

#define MFMA16(a, b, c) __builtin_amdgcn_mfma_f32_16x16x32_f16(a, b, c, 0, 0, 0)

__device__ __forceinline__ void load_lds16(const void* g, void* l) {
  __builtin_amdgcn_global_load_lds(
      (__attribute__((address_space(1))) void*)g,
      (__attribute__((address_space(3))) void*)l, 16, 0, 0);
}

// ============ prep kernel: cvt x, cvt ctx, 4 weight transposes, Vtg pad fill ============
// One kernel (block-range dispatch) replaces 7 launches (R11: saved ~21us of gaps).
__global__ __launch_bounds__(256) void k_prep(const float* __restrict__ x,
                                              const float* __restrict__ ctx,
                                              const float* __restrict__ Wq,
                                              const float* __restrict__ Wk,
                                              const float* __restrict__ Wv,
                                              const float* __restrict__ Wo,
                                              _Float16* __restrict__ xh,
                                              _Float16* __restrict__ ctxh,
                                              _Float16* __restrict__ Wqt,
                                              _Float16* __restrict__ Wkt,
                                              _Float16* __restrict__ Wvt,
                                              _Float16* __restrict__ Wot,
                                              _Float16* __restrict__ Vtg) {
  __shared__ float tile[64][65];
  const int b = blockIdx.x, t = threadIdx.x;

  if (b < 4096) {  // ---- cvt x: 33554432 f32 -> f16, 8/thread/iter
    for (int i = b * 256 + t; i < 4194304; i += 4096 * 256) {
      const float4* p = (const float4*)(x + (size_t)i * 8);
      float4 a = p[0], c = p[1];
      f16x8 v = {(_Float16)a.x, (_Float16)a.y, (_Float16)a.z, (_Float16)a.w,
                 (_Float16)c.x, (_Float16)c.y, (_Float16)c.z, (_Float16)c.w};
      *(f16x8*)(xh + (size_t)i * 8) = v;
    }
    return;
  }
  if (b < 4327) {  // ---- cvt ctx: 473088 f32 (231*256*8 exact)
    int i = (b - 4096) * 256 + t;
    const float4* p = (const float4*)(ctx + (size_t)i * 8);
    float4 a = p[0], c = p[1];
    f16x8 v = {(_Float16)a.x, (_Float16)a.y, (_Float16)a.z, (_Float16)a.w,
               (_Float16)c.x, (_Float16)c.y, (_Float16)c.z, (_Float16)c.w};
    *(f16x8*)(ctxh + (size_t)i * 8) = v;
    return;
  }
  if (b >= 5223) {  // ---- zero Vtg pad region (512 blocks * 256 * 16B = 2MB exact)
    int i = (b - 5223) * 256 + t;
    ((f16x8*)Vtg)[i] = f16x8{};
    return;
  }
  // ---- weight transpose+convert: in[K][N] f32 -> out[N][K] f16, 64x64 tiles
  const float* tin;
  _Float16* tout;
  int TK, TN, i;
  if (b < 4583)      { tin = Wq; tout = Wqt; TK = 1024; TN = 1024; i = b - 4327; }
  else if (b < 4775) { tin = Wk; tout = Wkt; TK = 768;  TN = 1024; i = b - 4583; }
  else if (b < 4967) { tin = Wv; tout = Wvt; TK = 768;  TN = 1024; i = b - 4775; }
  else               { tin = Wo; tout = Wot; TK = 1024; TN = 1024; i = b - 4967; }
  int n0 = (i & 15) * 64, k0 = (i >> 4) * 64;
  {
    int nn = t & 63, kb = t >> 6;
#pragma unroll
    for (int s = 0; s < 16; ++s) {
      int kk = kb + s * 4;
      tile[kk][nn] = tin[(size_t)(k0 + kk) * TN + n0 + nn];
    }
  }
  __syncthreads();
  {
    int kk = t & 63, nb = t >> 6;
#pragma unroll
    for (int s = 0; s < 16; ++s) {
      int nn = nb + s * 4;
      tout[(size_t)(n0 + nn) * TK + k0 + kk] = (_Float16)tile[kk][nn];
    }
  }
}

// ---------------- K/V projection: ctxh[616][768] @ W^T -> heads ----------------
__global__ __launch_bounds__(64) void k_kvproj(const _Float16* __restrict__ ctxh,
                                               const _Float16* __restrict__ Wkt,
                                               const _Float16* __restrict__ Wvt,
                                               _Float16* __restrict__ Kg,
                                               _Float16* __restrict__ Vtg) {
  int mt = blockIdx.x, nt = blockIdx.y;
  int lane = threadIdx.x;
  int l15 = lane & 15, lhi = lane >> 4;
  int arow = mt * 16 + l15;
  if (arow > 615) arow = 615;  // clamp; masked at write
  const _Float16* ap = ctxh + (size_t)arow * 768 + lhi * 8;
  const _Float16* kp = Wkt + (size_t)(nt * 16 + l15) * 768 + lhi * 8;
  const _Float16* vp = Wvt + (size_t)(nt * 16 + l15) * 768 + lhi * 8;
  f32x4 ak = {0.f, 0.f, 0.f, 0.f}, av = {0.f, 0.f, 0.f, 0.f};
#pragma unroll 4
  for (int ks = 0; ks < 24; ++ks) {
    f16x8 a = *(const f16x8*)(ap + ks * 32);
    f16x8 bk = *(const f16x8*)(kp + ks * 32);
    f16x8 bv = *(const f16x8*)(vp + ks * 32);
    ak = MFMA16(a, bk, ak);
    av = MFMA16(a, bv, av);
  }
  int n = nt * 16 + l15, h = n >> 6, d = n & 63;
#pragma unroll
  for (int j = 0; j < 4; ++j) {
    int gm = mt * 16 + lhi * 4 + j;
    if (gm < 616) {
      int b = gm / 77, m = gm - b * 77;
      Kg[((size_t)(b * 16 + h) * 77 + m) * 64 + d] = (_Float16)ak[j];
      Vtg[((size_t)(b * 16 + h) * 64 + d) * 128 + m] = (_Float16)av[j];
    }
  }
}

// ------------- attention: one block = one (b,h) x 128 query rows (8 waves) -------------
// R12: 128 rows/block halves K/V staging overhead (was re-staged per 64 rows).
// LDS = 10 + 16 + 32 KB = 58 KB -> 2 blocks/CU = 16 waves/CU (same as 64-row version).
__global__ __launch_bounds__(512) void k_attn(const _Float16* __restrict__ Qh,
                                              const _Float16* __restrict__ Kg,
                                              const _Float16* __restrict__ Vtg,
                                              _Float16* __restrict__ Out) {
  __shared__ __align__(16) char Kl[80 * 128];
  __shared__ __align__(16) char Vl[64 * 256];
  __shared__ __align__(16) char Pl[8 * 16 * 256];
  int bh = blockIdx.y, b = bh >> 4, h = bh & 15;
  int t = threadIdx.x, wid = t >> 6, lane = t & 63;
  int l15 = lane & 15, lhi = lane >> 4;

  const _Float16* Kgp = Kg + (size_t)bh * (77 * 64);
  const _Float16* Vgp = Vtg + (size_t)bh * (64 * 128);

  for (int idx = t; idx < 640; idx += 512) {
    int m = idx >> 3, c = (idx & 7) * 8;
    f16x8 v = {};
    if (m < 77) v = *(const f16x8*)(Kgp + m * 64 + c);
    *(f16x8*)(Kl + ((m * 128 + c * 2) ^ ((m & 7) << 4))) = v;
  }
  for (int idx = t; idx < 1024; idx += 512) {
    int d = idx >> 4, c = (idx & 15) * 8;
    f16x8 v = *(const f16x8*)(Vgp + d * 128 + c);
    *(f16x8*)(Vl + ((d * 256 + c * 2) ^ ((d & 7) << 4))) = v;
  }
  char* myP = Pl + wid * 4096;
#pragma unroll
  for (int i = 0; i < 4; ++i) *(f16x8*)(myP + lane * 64 + i * 16) = f16x8{};
  __syncthreads();

  int qrow = b * 4096 + blockIdx.x * 128 + wid * 16 + l15;
  const _Float16* qp = Qh + (size_t)qrow * 1024 + h * 64 + lhi * 8;
  f16x8 q0 = *(const f16x8*)qp;
  f16x8 q1 = *(const f16x8*)(qp + 32);

  float e[5][4];
  float mx[4] = {-1e30f, -1e30f, -1e30f, -1e30f};
#pragma unroll
  for (int ct = 0; ct < 5; ++ct) {
    int m = ct * 16 + l15;
    int d0b = lhi * 16;
    f16x8 k0 = *(const f16x8*)(Kl + ((m * 128 + d0b) ^ ((m & 7) << 4)));
    f16x8 k1 = *(const f16x8*)(Kl + ((m * 128 + 64 + d0b) ^ ((m & 7) << 4)));
    f32x4 acc = {0.f, 0.f, 0.f, 0.f};
    acc = MFMA16(q0, k0, acc);
    acc = MFMA16(q1, k1, acc);
    bool valid = m < 77;
#pragma unroll
    for (int j = 0; j < 4; ++j) {
      float v = valid ? acc[j] * 0.125f : -1e30f;
      e[ct][j] = v;
      mx[j] = fmaxf(mx[j], v);
    }
  }
#pragma unroll
  for (int off = 1; off < 16; off <<= 1)
#pragma unroll
    for (int j = 0; j < 4; ++j) mx[j] = fmaxf(mx[j], __shfl_xor(mx[j], off, 64));
  float sm[4] = {0.f, 0.f, 0.f, 0.f};
#pragma unroll
  for (int ct = 0; ct < 5; ++ct)
#pragma unroll
    for (int j = 0; j < 4; ++j) {
      float ev = __expf(e[ct][j] - mx[j]);
      e[ct][j] = ev;
      sm[j] += ev;
    }
#pragma unroll
  for (int off = 1; off < 16; off <<= 1)
#pragma unroll
    for (int j = 0; j < 4; ++j) sm[j] += __shfl_xor(sm[j], off, 64);
  float rs[4];
#pragma unroll
  for (int j = 0; j < 4; ++j) rs[j] = 1.0f / sm[j];

#pragma unroll
  for (int ct = 0; ct < 5; ++ct) {
    int m = ct * 16 + l15;
#pragma unroll
    for (int j = 0; j < 4; ++j) {
      int r = lhi * 4 + j;
      *(_Float16*)(myP + ((r * 256 + m * 2) ^ ((r & 7) << 4))) =
          (_Float16)(e[ct][j] * rs[j]);
    }
  }

  f32x4 o[4] = {{0.f,0.f,0.f,0.f},{0.f,0.f,0.f,0.f},{0.f,0.f,0.f,0.f},{0.f,0.f,0.f,0.f}};
#pragma unroll
  for (int ks = 0; ks < 3; ++ks) {
    int m0b = ks * 64 + lhi * 16;
    f16x8 pa = *(const f16x8*)(myP + ((l15 * 256 + m0b) ^ ((l15 & 7) << 4)));
#pragma unroll
    for (int dt = 0; dt < 4; ++dt) {
      int d = dt * 16 + l15;
      f16x8 vb = *(const f16x8*)(Vl + ((d * 256 + m0b) ^ ((d & 7) << 4)));
      o[dt] = MFMA16(pa, vb, o[dt]);
    }
  }
  _Float16* op = Out + (size_t)(b * 4096 + blockIdx.x * 128 + wid * 16) * 1024 + h * 64;
#pragma unroll
  for (int dt = 0; dt < 4; ++dt)
#pragma unroll
    for (int j = 0; j < 4; ++j) {
      int r = lhi * 4 + j;
      op[(size_t)r * 1024 + dt * 16 + l15] = (_Float16)o[dt][j];
    }
}

// ====== 256x256 GEMM (R9, 907 TF, 0 conflicts): 16x16 frags, cluster-pipelined ======
// reads + true double-buffer. R11 lesson: 32x32-fragment reads measure 4 bank-
// conflicts per ds_read_b128 regardless of swizzle (R4/R11); 16x16 + 3-bit swizzle
// + INT-offset addressing measures 0 (R8/R9). Reverted verbatim to R9.
template <int FINAL>
__global__ __launch_bounds__(512, 2) void k_gemm7(const _Float16* __restrict__ A,
                                                  const _Float16* __restrict__ Bt,
                                                  void* __restrict__ Cout,
                                                  const float* __restrict__ bias,
                                                  int M, int N, int K) {
  __shared__ __align__(16) char lds[131072];
  const int t = threadIdx.x, wid = t >> 6, lane = t & 63;
  const int wr = wid >> 2, wc = wid & 3;  // 2M x 4N wave grid
  const int l15 = lane & 15, lhi = lane >> 4;

  // T1: bijective XCD swizzle (nwg % 8 == 0)
  int nwg = gridDim.x, bid = blockIdx.x;
  int wg = ((nwg & 7) == 0) ? ((bid & 7) * (nwg >> 3) + (bid >> 3)) : bid;
  const int nTN = N >> 8;
  const int tm = wg / nTN, tn = wg % nTN;

  const _Float16* Ag = A + (size_t)tm * 256 * K;
  const _Float16* Bg = Bt + (size_t)tn * 256 * K;
  const size_t stg = (size_t)(wid * 8 + (lane >> 3)) * K +
                     (size_t)(((lane & 7) ^ ((lane >> 3) & 7)) * 8);
  const int dstg = wid * 1024;  // linear wave dest (HW adds lane*16)

  // read swizzle as int offsets: chunk(kk) = (kk*4 + lhi) ^ (l15&7)
  const int x7 = l15 & 7;
  const int cs0 = (lhi ^ x7) << 4;
  const int cs1 = ((4 + lhi) ^ x7) << 4;
  const int aoff = wr * 16384 + l15 * 128;
  const int boff = 32768 + wc * 8192 + l15 * 128;

  f32x4 acc[8][4];
#pragma unroll
  for (int i = 0; i < 8; ++i)
#pragma unroll
    for (int j = 0; j < 4; ++j) acc[i][j] = f32x4{0.f, 0.f, 0.f, 0.f};
  f16x8 a0k0[4], a0k1[4], a1k0[4], a1k1[4];
  f16x8 b00[2], b01[2], b10[2], b11[2];

#define STG_A(T, RB) load_lds16(Ag + stg + (size_t)(RB) * K + (T) * 64, \
                                lds + ((T) & 1) * 65536 + (RB) * 128 + dstg)
#define STG_B(T, RB) load_lds16(Bg + stg + (size_t)(RB) * K + (T) * 64, \
                                lds + ((T) & 1) * 65536 + 32768 + (RB) * 128 + dstg)
#define STG_TILE(T) { STG_A(T, 0); STG_A(T, 64); STG_A(T, 128); STG_A(T, 192);  \
                      STG_B(T, 0); STG_B(T, 64); STG_B(T, 128); STG_B(T, 192); }
#define RDA(DST, BUF, MH, CS) { const int p_ = (BUF) * 65536 + aoff + (MH) * 8192; \
    _Pragma("unroll") for (int mf = 0; mf < 4; ++mf)                               \
      DST[mf] = *(const f16x8*)&lds[p_ + mf * 2048 + (CS)]; }
#define RDB(DST, BUF, NH, CS) { const int q_ = (BUF) * 65536 + boff + (NH) * 4096; \
    _Pragma("unroll") for (int nf = 0; nf < 2; ++nf)                               \
      DST[nf] = *(const f16x8*)&lds[q_ + nf * 2048 + (CS)]; }
#define MMC(MH, NH, AR, BR) { __builtin_amdgcn_s_setprio(1);                       \
    _Pragma("unroll") for (int mf = 0; mf < 4; ++mf)                               \
      _Pragma("unroll") for (int nf = 0; nf < 2; ++nf)                             \
        acc[(MH)*4+mf][(NH)*2+nf] = MFMA16(AR[mf], BR[nf],                         \
                                           acc[(MH)*4+mf][(NH)*2+nf]);             \
    __builtin_amdgcn_s_setprio(0); }
#define VM0 asm volatile("s_waitcnt vmcnt(0)" ::: "memory")
#define BAR __builtin_amdgcn_s_barrier()

#define TILE(BUF, T, STG_ON)                                                       \
  {                                                                                \
    VM0; BAR;                                                                      \
    RDA(a0k0, BUF, 0, cs0); RDB(b00, BUF, 0, cs0);                                 \
    RDB(b10, BUF, 1, cs0);                                                         \
    if (STG_ON) STG_TILE((T) + 1);                                                 \
    MMC(0, 0, a0k0, b00);                                                          \
    RDA(a1k0, BUF, 1, cs0); MMC(0, 1, a0k0, b10);                                  \
    RDA(a1k1, BUF, 1, cs1); MMC(1, 1, a1k0, b10);                                  \
    RDB(b01, BUF, 0, cs1);  MMC(1, 0, a1k0, b00);                                  \
    RDB(b11, BUF, 1, cs1);  MMC(1, 0, a1k1, b01);                                  \
    RDA(a0k1, BUF, 0, cs1); MMC(1, 1, a1k1, b11);                                  \
    MMC(0, 1, a0k1, b11);                                                          \
    MMC(0, 0, a0k1, b01);                                                          \
  }

  const int nT = K >> 6;  // 16 for K=1024 (even, >= 4)

  STG_TILE(0);  // prologue: tile 0 -> buf0

  for (int i = 0; i < (nT >> 1) - 1; ++i) {
    TILE(0, 2 * i, true);
    TILE(1, 2 * i + 1, true);
  }
  TILE(0, nT - 2, true);   // stages tile nT-1 -> buf1
  TILE(1, nT - 1, false);  // last tile: nothing to stage

  // ---- C write: 16x16 C-layout col = l15, row = lhi*4 + reg (verified m89)
  const long rbase = (long)tm * 256 + wr * 128;
  const int cbase = tn * 256 + wc * 64;
#pragma unroll
  for (int mf = 0; mf < 8; ++mf)
#pragma unroll
    for (int nf = 0; nf < 4; ++nf) {
      int c = cbase + nf * 16 + l15;
      float bv = FINAL ? bias[c] : 0.f;
#pragma unroll
      for (int j = 0; j < 4; ++j) {
        long r = rbase + mf * 16 + lhi * 4 + j;
        float v = acc[mf][nf][j];
        if (FINAL) ((float*)Cout)[r * N + c] = v + bv;
        else ((_Float16*)Cout)[r * N + c] = (_Float16)v;
      }
    }
#undef STG_A
#undef STG_B
#undef STG_TILE
#undef RDA
#undef RDB
#undef MMC
#undef TILE
#undef VM0
#undef BAR
}

extern "C" void kernel_launch(void* const* d_in, const int* in_sizes, int n_in,
                              void* d_out, int out_size, void* d_ws, size_t ws_size,
                              hipStream_t stream) {
  const float* x   = (const float*)d_in[0];
  const float* ctx = (const float*)d_in[1];
  const float* Wq  = (const float*)d_in[2];
  const float* Wk  = (const float*)d_in[3];
  const float* Wv  = (const float*)d_in[4];
  const float* Wo  = (const float*)d_in[5];
  const float* bo  = (const float*)d_in[6];

  char* ws = (char*)d_ws;
  _Float16* xh   = (_Float16*)(ws + 0);           // [32768][1024] x-f16; later attnOut
  _Float16* Wqt  = (_Float16*)(ws + 67108864);    // [1024][1024]
  _Float16* Wkt  = (_Float16*)(ws + 69206016);    // [1024][768]
  _Float16* Wvt  = (_Float16*)(ws + 70778880);    // [1024][768]
  _Float16* Wot  = (_Float16*)(ws + 72351744);    // [1024][1024]
  _Float16* ctxh = (_Float16*)(ws + 74448896);    // [616][768]
  _Float16* Kg   = (_Float16*)(ws + 75395072);    // [128][77][64]
  _Float16* Vtg  = (_Float16*)(ws + 76656640);    // [128][64][128]
  _Float16* Qh   = (_Float16*)d_out;              // [32768][1024] f16 scratch in d_out

  // prep: cvt x [0,4096) | cvt ctx [4096,4327) | T(Wq) [4327,4583) | T(Wk)
  // [4583,4775) | T(Wv) [4775,4967) | T(Wo) [4967,5223) | fill Vtg [5223,5735)
  k_prep<<<5735, 256, 0, stream>>>(x, ctx, Wq, Wk, Wv, Wo,
                                   xh, ctxh, Wqt, Wkt, Wvt, Wot, Vtg);
  k_kvproj<<<dim3(39, 64), 64, 0, stream>>>(ctxh, Wkt, Wvt, Kg, Vtg);
  // GEMM1: Q projection -> d_out (f16 scratch); grid 512 (%8==0 for T1)
  k_gemm7<0><<<dim3(512), dim3(512), 0, stream>>>(xh, Wqt, (void*)Qh, nullptr, 32768, 1024, 1024);
  // attention: reads Qh (d_out), writes attnOut -> xh; 128 q-rows/block
  k_attn<<<dim3(32, 128), 512, 0, stream>>>(Qh, Kg, Vtg, xh);
  // GEMM2: O projection + bias -> d_out (f32)
  k_gemm7<1><<<dim3(512), dim3(512), 0, stream>>>(xh, Wot, d_out, bo, 32768, 1024, 1024);
}